// Round 9
// baseline (224.976 us; speedup 1.0000x reference)
//
#include <hip/hip_runtime.h>
#include <math.h>

#define HIDDEN 128
#define MUL1   64
#define ACOLS  320   // HIDDEN + 3*MUL1
#define TBINS  4096
#define NWAVES 16384  // node_sg: 2048 blocks x 8 waves

typedef unsigned short ushort_t;
typedef __attribute__((ext_vector_type(8))) _Float16 f16x8;
typedef __attribute__((ext_vector_type(4))) float f32x4;

__device__ __forceinline__ unsigned short f2h(float x) {
  return __builtin_bit_cast(unsigned short, (_Float16)x);
}
__device__ __forceinline__ unsigned pack2h(float a, float b) {
  return (unsigned)f2h(a) | ((unsigned)f2h(b) << 16);
}
__device__ __forceinline__ float hlo(unsigned u) {
  return (float)__builtin_bit_cast(_Float16, (unsigned short)(u & 0xffffu));
}
__device__ __forceinline__ float hhi(unsigned u) {
  return (float)__builtin_bit_cast(_Float16, (unsigned short)(u >> 16));
}

// ---------------- K1: fused R_n table (packed fp16 lerp pairs) + receiver histogram
// Tq u32 entry (i*128+ch) = { lo fp16: val(i,ch), hi fp16: val(i+1,ch) }
__global__ __launch_bounds__(128) void tab_hist(const float* __restrict__ W1,
                                                const float* __restrict__ W2,
                                                ushort_t* __restrict__ TqB,
                                                const int* __restrict__ recv,
                                                int* __restrict__ cnt, int n_edges) {
  const int tid = threadIdx.x;
  if (blockIdx.x > TBINS) {   // histogram blocks
    const int e = (blockIdx.x - (TBINS + 1)) * 128 + tid;
    if (e < n_edges) atomicAdd(&cnt[recv[e]], 1);
    return;
  }
  __shared__ float hsh[64];
  const int i = blockIdx.x;        // 0..TBINS
  const float x = (float)i * (5.0f / TBINS);
  if (tid < 64) {
    const bool valid = (x > 0.0f) && (x < 5.0f);
    const float invx = valid ? (1.0f / x) : 0.0f;
    float z = 0.0f;
#pragma unroll
    for (int r = 0; r < 8; ++r) {
      float arg = (float)(r + 1) * 0.6283185307f * x;     // k*pi*x/5
      float rad = 0.6324555320f * sinf(arg) * invx;       // sqrt(2/5)*sin/x
      z += rad * (W1[r * 64 + tid] * 0.3535533906f);      // W1/sqrt(8)
    }
    float sg = 1.0f / (1.0f + expf(-z));
    hsh[tid] = 1.679177f * z * sg;
  }
  __syncthreads();
  float acc = 0.0f;
  for (int j = 0; j < 64; ++j)
    acc += hsh[j] * W2[j * HIDDEN + tid];
  acc *= 0.125f;                                          // W2/8
  const ushort_t a16 = f2h(acc);
  TqB[((size_t)i * HIDDEN + tid) * 2] = a16;              // lo slot of row i
  if (i >= 1)
    TqB[((size_t)(i - 1) * HIDDEN + tid) * 2 + 1] = a16;  // hi slot of row i-1
}

// ---------------- K1b: pack node_attrs f32 -> fp16x2 (halves gather traffic) ----
__global__ __launch_bounds__(256) void attrs_pack(const float* __restrict__ attrs,
                                                  unsigned* __restrict__ attrsB,
                                                  int n2) {
  const int i = blockIdx.x * 256 + threadIdx.x;
  if (i < n2) {
    const float2 v = ((const float2*)attrs)[i];
    attrsB[i] = pack2h(v.x, v.y);
  }
}

// ---------------- K2a: per-block exclusive scan (1024 elems/block) ----------------
__global__ __launch_bounds__(1024) void scan_blocks(const int* __restrict__ cnt,
                                                    int* __restrict__ partial,
                                                    int* __restrict__ bsums, int n) {
  __shared__ int buf[1024];
  const int t = threadIdx.x;
  const int i = blockIdx.x * 1024 + t;
  const int v = (i < n) ? cnt[i] : 0;
  buf[t] = v;
  __syncthreads();
  for (int d = 1; d < 1024; d <<= 1) {
    const int x = buf[t];
    const int y = (t >= d) ? buf[t - d] : 0;
    __syncthreads();
    buf[t] = x + y;
    __syncthreads();
  }
  if (i < n) partial[i] = buf[t] - v;          // block-local exclusive
  if (t == 1023) bsums[blockIdx.x] = buf[1023];
}

// ---------------- K2b: single-block scan of block sums; writes off[n]=total ------
__global__ __launch_bounds__(1024) void scan_sums(int* __restrict__ bsums, int nb,
                                                  int* __restrict__ off, int n) {
  __shared__ int buf[1024];
  const int t = threadIdx.x;
  const int v = (t < nb) ? bsums[t] : 0;
  buf[t] = v;
  __syncthreads();
  for (int d = 1; d < 1024; d <<= 1) {
    const int x = buf[t];
    const int y = (t >= d) ? buf[t - d] : 0;
    __syncthreads();
    buf[t] = x + y;
    __syncthreads();
  }
  if (t < nb) bsums[t] = buf[t] - v;           // exclusive block offsets
  if (t == nb - 1) off[n] = buf[t];            // grand total
}

// ---------------- K2c: off/cur = partial + block offset ----------------
__global__ __launch_bounds__(256) void scan_final(const int* __restrict__ partial,
                                                  const int* __restrict__ bsums,
                                                  int* __restrict__ off,
                                                  int* __restrict__ cur, int n) {
  const int i = blockIdx.x * 256 + threadIdx.x;
  if (i < n) {
    const int o = partial[i] + bsums[i >> 10];
    off[i] = o;
    cur[i] = o;
  }
}

// ---------------- K2d: edge-balanced wave partition: lb[w] = lower_bound(off, w*E/W)
__global__ __launch_bounds__(256) void wave_bounds(const int* __restrict__ off,
                                                   int* __restrict__ lb,
                                                   int n_nodes, int n_edges) {
  const int w = blockIdx.x * 256 + threadIdx.x;
  if (w > NWAVES) return;
  if (w == NWAVES) { lb[w] = n_nodes; return; }
  const long long target = ((long long)w * (long long)n_edges) / NWAVES;
  int lo = 0, hi = n_nodes;
  while (lo < hi) {
    const int mid = (lo + hi) >> 1;
    if ((long long)off[mid] < target) lo = mid + 1; else hi = mid;
  }
  lb[w] = lo;
}

// ---------------- K3: build sorted 32B edge records ----------------
__global__ void scatter_kernel(const int* __restrict__ eidx,
                               const float* __restrict__ evec,
                               const float* __restrict__ elen,
                               int* __restrict__ cur, float4* __restrict__ recs,
                               int n_edges) {
  const int e = blockIdx.x * blockDim.x + threadIdx.x;
  if (e >= n_edges) return;
  const int s = eidx[e], r = eidx[n_edges + e];
  const float x = elen[e];
  const float v0 = evec[3 * e], v1 = evec[3 * e + 1], v2 = evec[3 * e + 2];
  const float rn = rsqrtf(v0 * v0 + v1 * v1 + v2 * v2);
  const float u = x * ((float)TBINS / 5.0f);
  int i0 = (int)floorf(u);
  i0 = i0 < 0 ? 0 : (i0 > TBINS - 1 ? TBINS - 1 : i0);
  const float fr = u - (float)i0;
  const bool valid = (x > 0.0f) && (x < 5.0f);
  const float w0 = valid ? 1.0f - fr : 0.0f;
  const float w1 = valid ? fr : 0.0f;
  const int pos = atomicAdd(&cur[r], 1);
  recs[2 * pos]     = make_float4(__int_as_float(s), w0, w1, __int_as_float(i0));
  recs[2 * pos + 1] = make_float4(1.7320508076f * v1 * rn,   // unit[:, [1,2,0]]*sqrt3
                                  1.7320508076f * v2 * rn,
                                  1.7320508076f * v0 * rn, 0.0f);
}

// ---------------- K4: pre-scale weights -> single fp16 in MFMA B-frag order ----
// P ushort layout: W0f[16384] W1f[8192] Wmf[24576]  (96 KB total)
// frag element: P[base + ((nt*KF+q)*64 + lane)*8 + j] = W[(quad*8+j) + q*32][nt*16+col]
// Wm carries an extra 2^8 to compensate B0 stored as B0*2^-8 (fp16 overflow headroom).
__global__ __launch_bounds__(256) void pack_weights(
    const float* __restrict__ W0, const float* __restrict__ W1,
    const float* __restrict__ Wm, ushort_t* __restrict__ P) {
  const int idx = blockIdx.x * 256 + threadIdx.x;     // 0..49151
  const int j = idx & 7, lane = (idx >> 3) & 63;
  const int krow = (lane >> 4) * 8 + j, col = lane & 15;
  float v;
  if (idx < 16384) {
    const int tq = idx >> 9, nt = tq >> 2, q = tq & 3;
    v = W0[(krow + q * 32) * HIDDEN + nt * 16 + col] * 0.0883883476f;
  } else if (idx < 24576) {
    const int i2 = idx - 16384;
    const int tq = i2 >> 9, nt = tq >> 2, q = tq & 3;
    v = W1[(krow + q * 32) * MUL1 + nt * 16 + col] * 0.0883883476f;
  } else {
    const int i3 = idx - 24576;
    const int tq = i3 >> 9, nt = tq / 6, q = tq % 6;
    v = Wm[(krow + q * 32) * HIDDEN + nt * 16 + col] * 18.4752086f;  // 0.07217*256
  }
  P[idx] = f2h(v);
}

// ---------------- K5: pure gather: per node accumulate S (128) and G (128x3),
// write 1KB fp16 record. Scalarized uniform control (r8) + 8-edge epochs
// (16 gathers in flight, half the serial memory epochs) + 8-wave blocks for
// finer drain granularity. r8 arithmetic: ~41us vs ~10us issue floor = exposed
// epoch latency.
__global__ __launch_bounds__(512) void node_sg(
    const unsigned* __restrict__ attrsB, const unsigned* __restrict__ TqB,
    const float4* __restrict__ recs, const int* __restrict__ off,
    const int* __restrict__ lb, unsigned* __restrict__ SG, int n_nodes) {
  const int lane = threadIdx.x & 63;
  const int wid = __builtin_amdgcn_readfirstlane((blockIdx.x << 3) +
                                                 (threadIdx.x >> 6));
  const int nbeg = lb[wid], nend = lb[wid + 1];
  const unsigned* tqb = TqB + 2 * lane;     // per-lane bases, loop-invariant
  const unsigned* atb = attrsB + lane;
  for (int n = nbeg; n < nend; ++n) {
    const int beg = off[n], end = off[n + 1];
    const int cnt = end - beg;
    float Sa = 0.f, Sb = 0.f;
    float Ga0 = 0.f, Ga1 = 0.f, Ga2 = 0.f, Gb0 = 0.f, Gb1 = 0.f, Gb2 = 0.f;
    int i = beg;
    // ---- main: 8-edge epochs, unpredicated (uniform scalar control)
    const int m8 = beg + (cnt & ~7);
    for (; i < m8; i += 8) {
      float4 ra[8], rb[8];
#pragma unroll
      for (int b = 0; b < 8; ++b) {
        ra[b] = recs[2 * (i + b)];                  // uniform -> s_load
        rb[b] = recs[2 * (i + b) + 1];
      }
      uint2 tqv[8];
      unsigned avv[8];
#pragma unroll
      for (int b = 0; b < 8; ++b) {                 // 16 gathers in flight
        tqv[b] = *(const uint2*)(tqb + ((unsigned)__float_as_int(ra[b].w) << 7));
        avv[b] = atb[(unsigned)__float_as_int(ra[b].x) << 6];
      }
#pragma unroll
      for (int b = 0; b < 8; ++b) {
        const float Ra = ra[b].y * hlo(tqv[b].x) + ra[b].z * hhi(tqv[b].x);
        const float Rb = ra[b].y * hlo(tqv[b].y) + ra[b].z * hhi(tqv[b].y);
        const float la = hlo(avv[b]) * Ra, lb2 = hhi(avv[b]) * Rb;
        Sa += la; Sb += lb2;
        Ga0 += la * rb[b].x; Ga1 += la * rb[b].y; Ga2 += la * rb[b].z;
        Gb0 += lb2 * rb[b].x; Gb1 += lb2 * rb[b].y; Gb2 += lb2 * rb[b].z;
      }
    }
    // ---- 4-edge epoch if >=4 remain
    const int m4 = beg + (cnt & ~3);
    for (; i < m4; i += 4) {
      float4 ra[4], rb[4];
#pragma unroll
      for (int b = 0; b < 4; ++b) {
        ra[b] = recs[2 * (i + b)];
        rb[b] = recs[2 * (i + b) + 1];
      }
      uint2 tqv[4];
      unsigned avv[4];
#pragma unroll
      for (int b = 0; b < 4; ++b) {
        tqv[b] = *(const uint2*)(tqb + ((unsigned)__float_as_int(ra[b].w) << 7));
        avv[b] = atb[(unsigned)__float_as_int(ra[b].x) << 6];
      }
#pragma unroll
      for (int b = 0; b < 4; ++b) {
        const float Ra = ra[b].y * hlo(tqv[b].x) + ra[b].z * hhi(tqv[b].x);
        const float Rb = ra[b].y * hlo(tqv[b].y) + ra[b].z * hhi(tqv[b].y);
        const float la = hlo(avv[b]) * Ra, lb2 = hhi(avv[b]) * Rb;
        Sa += la; Sb += lb2;
        Ga0 += la * rb[b].x; Ga1 += la * rb[b].y; Ga2 += la * rb[b].z;
        Gb0 += lb2 * rb[b].x; Gb1 += lb2 * rb[b].y; Gb2 += lb2 * rb[b].z;
      }
    }
    // ---- tail: 0-3 single edges
    for (; i < end; ++i) {
      const float4 ra = recs[2 * i];
      const float4 rb = recs[2 * i + 1];
      const int s = __float_as_int(ra.x);
      const int i0 = __float_as_int(ra.w);
      const uint2 tq = *(const uint2*)(tqb + ((unsigned)i0 << 7));
      const unsigned av = atb[(unsigned)s << 6];
      const float Ra = ra.y * hlo(tq.x) + ra.z * hhi(tq.x);
      const float Rb = ra.y * hlo(tq.y) + ra.z * hhi(tq.y);
      const float la = hlo(av) * Ra, lb2 = hhi(av) * Rb;
      Sa += la; Sb += lb2;
      Ga0 += la * rb.x; Ga1 += la * rb.y; Ga2 += la * rb.z;
      Gb0 += lb2 * rb.x; Gb1 += lb2 * rb.y; Gb2 += lb2 * rb.z;
    }
    unsigned* srow = SG + (size_t)n * 256;        // 256 u32 = 512 fp16 per node
    srow[lane]       = pack2h(Sa, Sb);            // S[2l], S[2l+1]
    srow[64 + lane]  = pack2h(Ga0, Gb0);          // G_d0
    srow[128 + lane] = pack2h(Ga1, Gb1);          // G_d1
    srow[192 + lane] = pack2h(Ga2, Gb2);          // G_d2
  }
}

// ---------------- K6: wave-per-16-nodes MFMA (fp16 single precision):
// A0=S@W0', A1=G@W1', B0, c0+=B0@Wm'. 1-wave blocks; depth-3 register
// prefetch on the L2-resident P stream; no barrier (wave-private LDS,
// lgkmcnt ordering only); A1 stored as 12B dwordx3.
struct F3 { float x, y, z; };

__global__ __launch_bounds__(64, 2) void node_mfma(
    const ushort_t* __restrict__ SG, const ushort_t* __restrict__ P,
    float* __restrict__ out, int n_nodes) {
  __shared__ float B0s[16][196];      // B0 stage; stride 196 dw (2-way = free)
  const int lane = threadIdx.x & 63;
  const int tile = blockIdx.x;
  const int row = lane & 15, quad = lane >> 4;
  const int nA = min(tile * 16 + row, n_nodes - 1);   // clamped A-row node
  const ushort_t* sgA = SG + (size_t)nA * 512;
  const int cnode0 = tile * 16 + quad * 4;            // C-frag rows

  const ushort_t* W0f = P;            // 16384
  const ushort_t* W1f = P + 16384;    // 8192
  const ushort_t* Wmf = P + 24576;    // 24576

  // ---- A-side fragments (issued up front; S row + 3 G rows)
  f16x8 aS[4], aG[3][4];
#pragma unroll
  for (int q = 0; q < 4; ++q)
    aS[q] = *(const f16x8*)(sgA + quad * 8 + q * 32);
#pragma unroll
  for (int d = 0; d < 3; ++d)
#pragma unroll
    for (int q = 0; q < 4; ++q)
      aG[d][q] = *(const f16x8*)(sgA + 128 + d * 128 + quad * 8 + q * 32);

  f32x4 c0[8];
#pragma unroll
  for (int nt = 0; nt < 8; ++nt) c0[nt] = (f32x4){0.f, 0.f, 0.f, 0.f};
  f32x4 c1[3][4];
#pragma unroll
  for (int d = 0; d < 3; ++d)
#pragma unroll
    for (int nt = 0; nt < 4; ++nt) c1[d][nt] = (f32x4){0.f, 0.f, 0.f, 0.f};

  // ---- Phase 1: A0 = S @ W0' (M=16, N=128, K=128). depth-3 prefetch.
  {
    f16x8 pb[3][4];
#pragma unroll
    for (int nt = 0; nt < 2; ++nt)
#pragma unroll
      for (int q = 0; q < 4; ++q)
        pb[nt][q] = *(const f16x8*)(W0f + ((nt * 4 + q) * 64 + lane) * 8);
#pragma unroll
    for (int nt = 0; nt < 8; ++nt) {
      const int cur = nt % 3;
      if (nt < 6) {
        const int dst = (nt + 2) % 3;
#pragma unroll
        for (int q = 0; q < 4; ++q)
          pb[dst][q] = *(const f16x8*)(W0f + (((nt + 2) * 4 + q) * 64 + lane) * 8);
      }
#pragma unroll
      for (int q = 0; q < 4; ++q)
        c0[nt] = __builtin_amdgcn_mfma_f32_16x16x32_f16(aS[q], pb[cur][q], c0[nt], 0, 0, 0);
    }
  }

  // ---- Phase 2: A1_d = G_d @ W1' (3 x [M=16, N=64, K=128]). depth-3 prefetch.
  {
    f16x8 pb[3][4];
#pragma unroll
    for (int nt = 0; nt < 2; ++nt)
#pragma unroll
      for (int q = 0; q < 4; ++q)
        pb[nt][q] = *(const f16x8*)(W1f + ((nt * 4 + q) * 64 + lane) * 8);
#pragma unroll
    for (int nt = 0; nt < 4; ++nt) {
      const int cur = nt % 3;
      if (nt < 2) {
        const int dst = (nt + 2) % 3;
#pragma unroll
        for (int q = 0; q < 4; ++q)
          pb[dst][q] = *(const f16x8*)(W1f + (((nt + 2) * 4 + q) * 64 + lane) * 8);
      }
#pragma unroll
      for (int q = 0; q < 4; ++q)
#pragma unroll
        for (int d = 0; d < 3; ++d)
          c1[d][nt] = __builtin_amdgcn_mfma_f32_16x16x32_f16(aG[d][q], pb[cur][q], c1[d][nt], 0, 0, 0);
    }
  }

  // ---- store A1 (out cols 128+3m+d) as one 12B store per (nt,r)
#pragma unroll
  for (int nt = 0; nt < 4; ++nt) {
    const int m = nt * 16 + row;
#pragma unroll
    for (int r = 0; r < 4; ++r) {
      const int n = cnode0 + r;
      if (n < n_nodes) {
        F3 v3 = {c1[0][nt][r], c1[1][nt][r], c1[2][nt][r]};
        *(F3*)&out[(size_t)n * ACOLS + HIDDEN + 3 * m] = v3;
      }
    }
  }

  // ---- build B0*2^-8 in LDS (C-layout -> A-layout transpose via LDS).
  // 2^-4 on the linear value before squaring = exact 2^-8 on B0; compensated
  // by the 2^8 baked into Wmf. Keeps fp16 A-frags far from 65504.
#pragma unroll
  for (int nt = 0; nt < 8; ++nt)
#pragma unroll
    for (int r = 0; r < 4; ++r) {
      const float a = c0[nt][r] * 0.0625f;
      B0s[quad * 4 + r][nt * 16 + row] = a * a;
    }
#pragma unroll
  for (int nt = 0; nt < 4; ++nt)
#pragma unroll
    for (int r = 0; r < 4; ++r) {
      const float x = c1[0][nt][r] * 0.0625f, y = c1[1][nt][r] * 0.0625f,
                  z = c1[2][nt][r] * 0.0625f;
      B0s[quad * 4 + r][HIDDEN + nt * 16 + row] =
          (x * x + y * y + z * z) * 0.5773502692f;   // /sqrt(3), *2^-8
    }

  // ---- Phase 3: c0 += B0 @ Wm' (K=192). Issue q=0/1 B-frag loads BEFORE the
  // LDS wait so they fly during the A-side cvt work.
  f16x8 mh[3][8];
#pragma unroll
  for (int qq = 0; qq < 2; ++qq)
#pragma unroll
    for (int nt = 0; nt < 8; ++nt)
      mh[qq][nt] = *(const f16x8*)(Wmf + ((nt * 6 + qq) * 64 + lane) * 8);

  // wave-private LDS: only this wave's ds_writes must complete (no barrier,
  // keeps the global prefetches above in flight). sched_barrier pins order.
  asm volatile("s_waitcnt lgkmcnt(0)" ::: "memory");
  __builtin_amdgcn_sched_barrier(0);

  f16x8 ahq[6];
#pragma unroll
  for (int q = 0; q < 6; ++q) {
    const float* src = &B0s[row][quad * 8 + q * 32];
#pragma unroll
    for (int j = 0; j < 8; ++j) ahq[q][j] = (_Float16)src[j];
  }
#pragma unroll
  for (int q = 0; q < 6; ++q) {
    const int cur = q % 3;
    if (q < 4) {
      const int dst = (q + 2) % 3;
#pragma unroll
      for (int nt = 0; nt < 8; ++nt)
        mh[dst][nt] = *(const f16x8*)(Wmf + ((nt * 6 + (q + 2)) * 64 + lane) * 8);
    }
#pragma unroll
    for (int nt = 0; nt < 8; ++nt)
      c0[nt] = __builtin_amdgcn_mfma_f32_16x16x32_f16(ahq[q], mh[cur][nt], c0[nt], 0, 0, 0);
  }

  // ---- store out[:, :128] = A0 + mix0 (64B-coalesced per quad group)
#pragma unroll
  for (int nt = 0; nt < 8; ++nt)
#pragma unroll
    for (int r = 0; r < 4; ++r) {
      const int n = cnode0 + r;
      if (n < n_nodes) out[(size_t)n * ACOLS + nt * 16 + row] = c0[nt][r];
    }
}

extern "C" void kernel_launch(void* const* d_in, const int* in_sizes, int n_in,
                              void* d_out, int out_size, void* d_ws, size_t ws_size,
                              hipStream_t stream) {
  const float* attrs = (const float*)d_in[0];
  const int*   eidx  = (const int*)d_in[1];
  const float* evec  = (const float*)d_in[2];
  const float* elen  = (const float*)d_in[3];
  const float* W1    = (const float*)d_in[4];
  const float* W2    = (const float*)d_in[5];
  const float* Wtp0  = (const float*)d_in[6];
  const float* Wtp1  = (const float*)d_in[7];
  const float* Wmix  = (const float*)d_in[8];
  float* out = (float*)d_out;

  const int n_nodes = in_sizes[0] / HIDDEN;
  const int n_edges = in_sizes[1] / 2;

  // ws: recs | TqB | cnt | off | cur | partial | bsums | lb | SG | P(96KB) | attrsB
  char* ws = (char*)d_ws;
  float4* recs = (float4*)ws;
  size_t o1 = (((size_t)n_edges * 32) + 255) & ~(size_t)255;
  ushort_t* TqB = (ushort_t*)(ws + o1);                       // (TBINS+1)*128 u32
  size_t o2 = (o1 + (size_t)(TBINS + 1) * HIDDEN * 4 + 255) & ~(size_t)255;
  int* cnt = (int*)(ws + o2);
  size_t o3 = (o2 + (size_t)n_nodes * 4 + 255) & ~(size_t)255;
  int* off = (int*)(ws + o3);
  size_t o4 = (o3 + (size_t)(n_nodes + 1) * 4 + 255) & ~(size_t)255;
  int* cur = (int*)(ws + o4);
  size_t o5 = (o4 + (size_t)n_nodes * 4 + 255) & ~(size_t)255;
  int* partial = (int*)(ws + o5);
  size_t o6 = (o5 + (size_t)n_nodes * 4 + 255) & ~(size_t)255;
  int* bsums = (int*)(ws + o6);
  size_t o6b = o6 + 1024 * 4;
  int* lb = (int*)(ws + o6b);                                 // NWAVES+1 ints
  size_t o7 = (o6b + (size_t)(NWAVES + 1) * 4 + 255) & ~(size_t)255;
  unsigned* SG = (unsigned*)(ws + o7);
  size_t o8 = o7 + (size_t)n_nodes * 1024;
  ushort_t* P = (ushort_t*)(ws + o8);
  size_t o9 = (o8 + 49152 * 2 + 255) & ~(size_t)255;
  unsigned* attrsB = (unsigned*)(ws + o9);                    // n_nodes*64 u32

  (void)hipMemsetAsync(cnt, 0, (size_t)n_nodes * 4, stream);
  const int n2 = n_nodes * 64;
  attrs_pack<<<(n2 + 255) / 256, 256, 0, stream>>>(attrs, attrsB, n2);
  const int hist_blocks = (n_edges + 127) / 128;
  tab_hist<<<TBINS + 1 + hist_blocks, 128, 0, stream>>>(W1, W2, TqB,
                                                        eidx + n_edges, cnt, n_edges);
  const int nscan = (n_nodes + 1023) / 1024;
  scan_blocks<<<nscan, 1024, 0, stream>>>(cnt, partial, bsums, n_nodes);
  scan_sums<<<1, 1024, 0, stream>>>(bsums, nscan, off, n_nodes);
  scan_final<<<(n_nodes + 255) / 256, 256, 0, stream>>>(partial, bsums, off, cur,
                                                        n_nodes);
  wave_bounds<<<(NWAVES + 1 + 255) / 256, 256, 0, stream>>>(off, lb, n_nodes,
                                                            n_edges);
  scatter_kernel<<<(n_edges + 255) / 256, 256, 0, stream>>>(eidx, evec, elen, cur,
                                                            recs, n_edges);
  pack_weights<<<192, 256, 0, stream>>>(Wtp0, Wtp1, Wmix, P);
  node_sg<<<2048, 512, 0, stream>>>(attrsB, (const unsigned*)TqB, recs, off, lb,
                                    SG, n_nodes);
  const int ntiles = (n_nodes + 15) / 16;
  node_mfma<<<ntiles, 64, 0, stream>>>((const ushort_t*)SG, P, out, n_nodes);
}

// Round 10
// 222.448 us; speedup vs baseline: 1.0114x; 1.0114x over previous
//
#include <hip/hip_runtime.h>
#include <math.h>

#define HIDDEN 128
#define MUL1   64
#define ACOLS  320   // HIDDEN + 3*MUL1
#define TBINS  4096
#define NWAVES 16384  // node_sg: 2048 blocks x 8 waves

typedef unsigned short ushort_t;
typedef __attribute__((ext_vector_type(8))) _Float16 f16x8;
typedef __attribute__((ext_vector_type(4))) float f32x4;

__device__ __forceinline__ unsigned short f2h(float x) {
  return __builtin_bit_cast(unsigned short, (_Float16)x);
}
__device__ __forceinline__ unsigned pack2h(float a, float b) {
  return (unsigned)f2h(a) | ((unsigned)f2h(b) << 16);
}
__device__ __forceinline__ float hlo(unsigned u) {
  return (float)__builtin_bit_cast(_Float16, (unsigned short)(u & 0xffffu));
}
__device__ __forceinline__ float hhi(unsigned u) {
  return (float)__builtin_bit_cast(_Float16, (unsigned short)(u >> 16));
}

// ---------------- K1: fused R_n table (packed fp16 lerp pairs) + receiver
// histogram + attrs f32->fp16x2 pack (3-range block multiplex; all independent).
__global__ __launch_bounds__(128) void tab_hist(const float* __restrict__ W1,
                                                const float* __restrict__ W2,
                                                ushort_t* __restrict__ TqB,
                                                const int* __restrict__ recv,
                                                int* __restrict__ cnt, int n_edges,
                                                const float* __restrict__ attrs,
                                                unsigned* __restrict__ attrsB,
                                                int n2, int hist_blocks) {
  const int tid = threadIdx.x;
  if (blockIdx.x > TBINS) {
    const int hb = blockIdx.x - (TBINS + 1);
    if (hb < hist_blocks) {                      // histogram range
      const int e = hb * 128 + tid;
      if (e < n_edges) atomicAdd(&cnt[recv[e]], 1);
    } else {                                     // attrs pack range
      const int i = (hb - hist_blocks) * 128 + tid;
      if (i < n2) {
        const float2 v = ((const float2*)attrs)[i];
        attrsB[i] = pack2h(v.x, v.y);
      }
    }
    return;
  }
  __shared__ float hsh[64];
  const int i = blockIdx.x;        // 0..TBINS
  const float x = (float)i * (5.0f / TBINS);
  if (tid < 64) {
    const bool valid = (x > 0.0f) && (x < 5.0f);
    const float invx = valid ? (1.0f / x) : 0.0f;
    float z = 0.0f;
#pragma unroll
    for (int r = 0; r < 8; ++r) {
      float arg = (float)(r + 1) * 0.6283185307f * x;     // k*pi*x/5
      float rad = 0.6324555320f * sinf(arg) * invx;       // sqrt(2/5)*sin/x
      z += rad * (W1[r * 64 + tid] * 0.3535533906f);      // W1/sqrt(8)
    }
    float sg = 1.0f / (1.0f + expf(-z));
    hsh[tid] = 1.679177f * z * sg;
  }
  __syncthreads();
  float acc = 0.0f;
  for (int j = 0; j < 64; ++j)
    acc += hsh[j] * W2[j * HIDDEN + tid];
  acc *= 0.125f;                                          // W2/8
  const ushort_t a16 = f2h(acc);
  TqB[((size_t)i * HIDDEN + tid) * 2] = a16;              // lo slot of row i
  if (i >= 1)
    TqB[((size_t)(i - 1) * HIDDEN + tid) * 2 + 1] = a16;  // hi slot of row i-1
}

// ---------------- K2a: per-block exclusive scan (1024 elems/block) ----------------
__global__ __launch_bounds__(1024) void scan_blocks(const int* __restrict__ cnt,
                                                    int* __restrict__ partial,
                                                    int* __restrict__ bsums, int n) {
  __shared__ int buf[1024];
  const int t = threadIdx.x;
  const int i = blockIdx.x * 1024 + t;
  const int v = (i < n) ? cnt[i] : 0;
  buf[t] = v;
  __syncthreads();
  for (int d = 1; d < 1024; d <<= 1) {
    const int x = buf[t];
    const int y = (t >= d) ? buf[t - d] : 0;
    __syncthreads();
    buf[t] = x + y;
    __syncthreads();
  }
  if (i < n) partial[i] = buf[t] - v;          // block-local exclusive
  if (t == 1023) bsums[blockIdx.x] = buf[1023];
}

// ---------------- K2b: single-block scan of block sums; writes off[n]=total ------
__global__ __launch_bounds__(1024) void scan_sums(int* __restrict__ bsums, int nb,
                                                  int* __restrict__ off, int n) {
  __shared__ int buf[1024];
  const int t = threadIdx.x;
  const int v = (t < nb) ? bsums[t] : 0;
  buf[t] = v;
  __syncthreads();
  for (int d = 1; d < 1024; d <<= 1) {
    const int x = buf[t];
    const int y = (t >= d) ? buf[t - d] : 0;
    __syncthreads();
    buf[t] = x + y;
    __syncthreads();
  }
  if (t < nb) bsums[t] = buf[t] - v;           // exclusive block offsets
  if (t == nb - 1) off[n] = buf[t];            // grand total
}

// ---------------- K2c: off/cur = partial + block offset ----------------
__global__ __launch_bounds__(256) void scan_final(const int* __restrict__ partial,
                                                  const int* __restrict__ bsums,
                                                  int* __restrict__ off,
                                                  int* __restrict__ cur, int n) {
  const int i = blockIdx.x * 256 + threadIdx.x;
  if (i < n) {
    const int o = partial[i] + bsums[i >> 10];
    off[i] = o;
    cur[i] = o;
  }
}

// ---------------- K3: build sorted 32B edge records + edge-balanced wave
// partition lb[w] = lower_bound(off, w*E/W)  (2-range multiplex; both need
// only scan_final's outputs).
__global__ __launch_bounds__(256) void scatter_kernel(
    const int* __restrict__ eidx, const float* __restrict__ evec,
    const float* __restrict__ elen, int* __restrict__ cur,
    float4* __restrict__ recs, int n_edges,
    const int* __restrict__ off, int* __restrict__ lb, int n_nodes,
    int edge_blocks) {
  if (blockIdx.x >= edge_blocks) {               // wave-partition range
    const int w = (blockIdx.x - edge_blocks) * 256 + threadIdx.x;
    if (w > NWAVES) return;
    if (w == NWAVES) { lb[w] = n_nodes; return; }
    const long long target = ((long long)w * (long long)n_edges) / NWAVES;
    int lo = 0, hi = n_nodes;
    while (lo < hi) {
      const int mid = (lo + hi) >> 1;
      if ((long long)off[mid] < target) lo = mid + 1; else hi = mid;
    }
    lb[w] = lo;
    return;
  }
  const int e = blockIdx.x * 256 + threadIdx.x;
  if (e >= n_edges) return;
  const int s = eidx[e], r = eidx[n_edges + e];
  const float x = elen[e];
  const float v0 = evec[3 * e], v1 = evec[3 * e + 1], v2 = evec[3 * e + 2];
  const float rn = rsqrtf(v0 * v0 + v1 * v1 + v2 * v2);
  const float u = x * ((float)TBINS / 5.0f);
  int i0 = (int)floorf(u);
  i0 = i0 < 0 ? 0 : (i0 > TBINS - 1 ? TBINS - 1 : i0);
  const float fr = u - (float)i0;
  const bool valid = (x > 0.0f) && (x < 5.0f);
  const float w0 = valid ? 1.0f - fr : 0.0f;
  const float w1 = valid ? fr : 0.0f;
  const int pos = atomicAdd(&cur[r], 1);
  recs[2 * pos]     = make_float4(__int_as_float(s), w0, w1, __int_as_float(i0));
  recs[2 * pos + 1] = make_float4(1.7320508076f * v1 * rn,   // unit[:, [1,2,0]]*sqrt3
                                  1.7320508076f * v2 * rn,
                                  1.7320508076f * v0 * rn, 0.0f);
}

// ---------------- K4: pre-scale weights -> single fp16 in MFMA B-frag order ----
// P ushort layout: W0f[16384] W1f[8192] Wmf[24576]  (96 KB total)
// frag element: P[base + ((nt*KF+q)*64 + lane)*8 + j] = W[(quad*8+j) + q*32][nt*16+col]
// Wm carries an extra 2^8 to compensate B0 stored as B0*2^-8 (fp16 overflow headroom).
__global__ __launch_bounds__(256) void pack_weights(
    const float* __restrict__ W0, const float* __restrict__ W1,
    const float* __restrict__ Wm, ushort_t* __restrict__ P) {
  const int idx = blockIdx.x * 256 + threadIdx.x;     // 0..49151
  const int j = idx & 7, lane = (idx >> 3) & 63;
  const int krow = (lane >> 4) * 8 + j, col = lane & 15;
  float v;
  if (idx < 16384) {
    const int tq = idx >> 9, nt = tq >> 2, q = tq & 3;
    v = W0[(krow + q * 32) * HIDDEN + nt * 16 + col] * 0.0883883476f;
  } else if (idx < 24576) {
    const int i2 = idx - 16384;
    const int tq = i2 >> 9, nt = tq >> 2, q = tq & 3;
    v = W1[(krow + q * 32) * MUL1 + nt * 16 + col] * 0.0883883476f;
  } else {
    const int i3 = idx - 24576;
    const int tq = i3 >> 9, nt = tq / 6, q = tq % 6;
    v = Wm[(krow + q * 32) * HIDDEN + nt * 16 + col] * 18.4752086f;  // 0.07217*256
  }
  P[idx] = f2h(v);
}

// ---------------- K5: pure gather: per node accumulate S (128) and G (128x3),
// write 1KB fp16 record. Scalarized uniform control + 8-edge epochs
// (16 gathers in flight). At its TA/gather floor (r9: ILP/balance knobs null).
__global__ __launch_bounds__(512) void node_sg(
    const unsigned* __restrict__ attrsB, const unsigned* __restrict__ TqB,
    const float4* __restrict__ recs, const int* __restrict__ off,
    const int* __restrict__ lb, unsigned* __restrict__ SG, int n_nodes) {
  const int lane = threadIdx.x & 63;
  const int wid = __builtin_amdgcn_readfirstlane((blockIdx.x << 3) +
                                                 (threadIdx.x >> 6));
  const int nbeg = lb[wid], nend = lb[wid + 1];
  const unsigned* tqb = TqB + 2 * lane;     // per-lane bases, loop-invariant
  const unsigned* atb = attrsB + lane;
  for (int n = nbeg; n < nend; ++n) {
    const int beg = off[n], end = off[n + 1];
    const int cnt = end - beg;
    float Sa = 0.f, Sb = 0.f;
    float Ga0 = 0.f, Ga1 = 0.f, Ga2 = 0.f, Gb0 = 0.f, Gb1 = 0.f, Gb2 = 0.f;
    int i = beg;
    // ---- main: 8-edge epochs, unpredicated (uniform scalar control)
    const int m8 = beg + (cnt & ~7);
    for (; i < m8; i += 8) {
      float4 ra[8], rb[8];
#pragma unroll
      for (int b = 0; b < 8; ++b) {
        ra[b] = recs[2 * (i + b)];                  // uniform -> s_load
        rb[b] = recs[2 * (i + b) + 1];
      }
      uint2 tqv[8];
      unsigned avv[8];
#pragma unroll
      for (int b = 0; b < 8; ++b) {                 // 16 gathers in flight
        tqv[b] = *(const uint2*)(tqb + ((unsigned)__float_as_int(ra[b].w) << 7));
        avv[b] = atb[(unsigned)__float_as_int(ra[b].x) << 6];
      }
#pragma unroll
      for (int b = 0; b < 8; ++b) {
        const float Ra = ra[b].y * hlo(tqv[b].x) + ra[b].z * hhi(tqv[b].x);
        const float Rb = ra[b].y * hlo(tqv[b].y) + ra[b].z * hhi(tqv[b].y);
        const float la = hlo(avv[b]) * Ra, lb2 = hhi(avv[b]) * Rb;
        Sa += la; Sb += lb2;
        Ga0 += la * rb[b].x; Ga1 += la * rb[b].y; Ga2 += la * rb[b].z;
        Gb0 += lb2 * rb[b].x; Gb1 += lb2 * rb[b].y; Gb2 += lb2 * rb[b].z;
      }
    }
    // ---- 4-edge epoch if >=4 remain
    const int m4 = beg + (cnt & ~3);
    for (; i < m4; i += 4) {
      float4 ra[4], rb[4];
#pragma unroll
      for (int b = 0; b < 4; ++b) {
        ra[b] = recs[2 * (i + b)];
        rb[b] = recs[2 * (i + b) + 1];
      }
      uint2 tqv[4];
      unsigned avv[4];
#pragma unroll
      for (int b = 0; b < 4; ++b) {
        tqv[b] = *(const uint2*)(tqb + ((unsigned)__float_as_int(ra[b].w) << 7));
        avv[b] = atb[(unsigned)__float_as_int(ra[b].x) << 6];
      }
#pragma unroll
      for (int b = 0; b < 4; ++b) {
        const float Ra = ra[b].y * hlo(tqv[b].x) + ra[b].z * hhi(tqv[b].x);
        const float Rb = ra[b].y * hlo(tqv[b].y) + ra[b].z * hhi(tqv[b].y);
        const float la = hlo(avv[b]) * Ra, lb2 = hhi(avv[b]) * Rb;
        Sa += la; Sb += lb2;
        Ga0 += la * rb[b].x; Ga1 += la * rb[b].y; Ga2 += la * rb[b].z;
        Gb0 += lb2 * rb[b].x; Gb1 += lb2 * rb[b].y; Gb2 += lb2 * rb[b].z;
      }
    }
    // ---- tail: 0-3 single edges
    for (; i < end; ++i) {
      const float4 ra = recs[2 * i];
      const float4 rb = recs[2 * i + 1];
      const int s = __float_as_int(ra.x);
      const int i0 = __float_as_int(ra.w);
      const uint2 tq = *(const uint2*)(tqb + ((unsigned)i0 << 7));
      const unsigned av = atb[(unsigned)s << 6];
      const float Ra = ra.y * hlo(tq.x) + ra.z * hhi(tq.x);
      const float Rb = ra.y * hlo(tq.y) + ra.z * hhi(tq.y);
      const float la = hlo(av) * Ra, lb2 = hhi(av) * Rb;
      Sa += la; Sb += lb2;
      Ga0 += la * rb.x; Ga1 += la * rb.y; Ga2 += la * rb.z;
      Gb0 += lb2 * rb.x; Gb1 += lb2 * rb.y; Gb2 += lb2 * rb.z;
    }
    unsigned* srow = SG + (size_t)n * 256;        // 256 u32 = 512 fp16 per node
    srow[lane]       = pack2h(Sa, Sb);            // S[2l], S[2l+1]
    srow[64 + lane]  = pack2h(Ga0, Gb0);          // G_d0
    srow[128 + lane] = pack2h(Ga1, Gb1);          // G_d1
    srow[192 + lane] = pack2h(Ga2, Gb2);          // G_d2
  }
}

// ---------------- K6: wave-per-16-nodes MFMA (fp16 single precision):
// A0=S@W0', A1=G@W1', B0, c0+=B0@Wm'. 1-wave blocks; depth-3 register
// prefetch on the L2-resident P stream. B0s staged as fp16 (6.4 KB vs 12.8 KB
// f32): doubles the LDS block cap (r9: LDS_Block_Size=12800 -> 12 blocks/CU
// ceiling) and phase 3 reads A-frags with one ds_read_b128, no cvt chain.
// Values pass through fp16 in phase 3 either way -> numerics identical.
struct F3 { float x, y, z; };

__global__ __launch_bounds__(64, 2) void node_mfma(
    const ushort_t* __restrict__ SG, const ushort_t* __restrict__ P,
    float* __restrict__ out, int n_nodes) {
  __shared__ ushort_t B0s[16][200];   // fp16 B0 stage; stride 200 (400B, 16B-aligned rows)
  const int lane = threadIdx.x & 63;
  const int tile = blockIdx.x;
  const int row = lane & 15, quad = lane >> 4;
  const int nA = min(tile * 16 + row, n_nodes - 1);   // clamped A-row node
  const ushort_t* sgA = SG + (size_t)nA * 512;
  const int cnode0 = tile * 16 + quad * 4;            // C-frag rows

  const ushort_t* W0f = P;            // 16384
  const ushort_t* W1f = P + 16384;    // 8192
  const ushort_t* Wmf = P + 24576;    // 24576

  // ---- A-side fragments (issued up front; S row + 3 G rows)
  f16x8 aS[4], aG[3][4];
#pragma unroll
  for (int q = 0; q < 4; ++q)
    aS[q] = *(const f16x8*)(sgA + quad * 8 + q * 32);
#pragma unroll
  for (int d = 0; d < 3; ++d)
#pragma unroll
    for (int q = 0; q < 4; ++q)
      aG[d][q] = *(const f16x8*)(sgA + 128 + d * 128 + quad * 8 + q * 32);

  f32x4 c0[8];
#pragma unroll
  for (int nt = 0; nt < 8; ++nt) c0[nt] = (f32x4){0.f, 0.f, 0.f, 0.f};
  f32x4 c1[3][4];
#pragma unroll
  for (int d = 0; d < 3; ++d)
#pragma unroll
    for (int nt = 0; nt < 4; ++nt) c1[d][nt] = (f32x4){0.f, 0.f, 0.f, 0.f};

  // ---- Phase 1: A0 = S @ W0' (M=16, N=128, K=128). depth-3 prefetch.
  {
    f16x8 pb[3][4];
#pragma unroll
    for (int nt = 0; nt < 2; ++nt)
#pragma unroll
      for (int q = 0; q < 4; ++q)
        pb[nt][q] = *(const f16x8*)(W0f + ((nt * 4 + q) * 64 + lane) * 8);
#pragma unroll
    for (int nt = 0; nt < 8; ++nt) {
      const int cur = nt % 3;
      if (nt < 6) {
        const int dst = (nt + 2) % 3;
#pragma unroll
        for (int q = 0; q < 4; ++q)
          pb[dst][q] = *(const f16x8*)(W0f + (((nt + 2) * 4 + q) * 64 + lane) * 8);
      }
#pragma unroll
      for (int q = 0; q < 4; ++q)
        c0[nt] = __builtin_amdgcn_mfma_f32_16x16x32_f16(aS[q], pb[cur][q], c0[nt], 0, 0, 0);
    }
  }

  // ---- Phase 2: A1_d = G_d @ W1' (3 x [M=16, N=64, K=128]). depth-3 prefetch.
  {
    f16x8 pb[3][4];
#pragma unroll
    for (int nt = 0; nt < 2; ++nt)
#pragma unroll
      for (int q = 0; q < 4; ++q)
        pb[nt][q] = *(const f16x8*)(W1f + ((nt * 4 + q) * 64 + lane) * 8);
#pragma unroll
    for (int nt = 0; nt < 4; ++nt) {
      const int cur = nt % 3;
      if (nt < 2) {
        const int dst = (nt + 2) % 3;
#pragma unroll
        for (int q = 0; q < 4; ++q)
          pb[dst][q] = *(const f16x8*)(W1f + (((nt + 2) * 4 + q) * 64 + lane) * 8);
      }
#pragma unroll
      for (int q = 0; q < 4; ++q)
#pragma unroll
        for (int d = 0; d < 3; ++d)
          c1[d][nt] = __builtin_amdgcn_mfma_f32_16x16x32_f16(aG[d][q], pb[cur][q], c1[d][nt], 0, 0, 0);
    }
  }

  // ---- store A1 (out cols 128+3m+d) as one 12B store per (nt,r)
#pragma unroll
  for (int nt = 0; nt < 4; ++nt) {
    const int m = nt * 16 + row;
#pragma unroll
    for (int r = 0; r < 4; ++r) {
      const int n = cnode0 + r;
      if (n < n_nodes) {
        F3 v3 = {c1[0][nt][r], c1[1][nt][r], c1[2][nt][r]};
        *(F3*)&out[(size_t)n * ACOLS + HIDDEN + 3 * m] = v3;
      }
    }
  }

  // ---- build B0*2^-8 (fp16) in LDS (C-layout -> A-layout transpose).
  // 2^-4 on the linear value before squaring = exact 2^-8 on B0; compensated
  // by the 2^8 baked into Wmf.
#pragma unroll
  for (int nt = 0; nt < 8; ++nt)
#pragma unroll
    for (int r = 0; r < 4; ++r) {
      const float a = c0[nt][r] * 0.0625f;
      B0s[quad * 4 + r][nt * 16 + row] = f2h(a * a);
    }
#pragma unroll
  for (int nt = 0; nt < 4; ++nt)
#pragma unroll
    for (int r = 0; r < 4; ++r) {
      const float x = c1[0][nt][r] * 0.0625f, y = c1[1][nt][r] * 0.0625f,
                  z = c1[2][nt][r] * 0.0625f;
      B0s[quad * 4 + r][HIDDEN + nt * 16 + row] =
          f2h((x * x + y * y + z * z) * 0.5773502692f);   // /sqrt(3), *2^-8
    }

  // ---- Phase 3: c0 += B0 @ Wm' (K=192). Issue q=0/1 B-frag loads BEFORE the
  // LDS wait so they fly during the LDS drain.
  f16x8 mh[3][8];
#pragma unroll
  for (int qq = 0; qq < 2; ++qq)
#pragma unroll
    for (int nt = 0; nt < 8; ++nt)
      mh[qq][nt] = *(const f16x8*)(Wmf + ((nt * 6 + qq) * 64 + lane) * 8);

  // wave-private LDS: only this wave's ds_writes must complete (no barrier,
  // keeps the global prefetches above in flight). sched_barrier pins order.
  asm volatile("s_waitcnt lgkmcnt(0)" ::: "memory");
  __builtin_amdgcn_sched_barrier(0);

#pragma unroll
  for (int q = 0; q < 6; ++q) {
    const int cur = q % 3;
    if (q < 4) {
      const int dst = (q + 2) % 3;
#pragma unroll
      for (int nt = 0; nt < 8; ++nt)
        mh[dst][nt] = *(const f16x8*)(Wmf + ((nt * 6 + (q + 2)) * 64 + lane) * 8);
    }
    const f16x8 ah = *(const f16x8*)&B0s[row][quad * 8 + q * 32];  // ds_read_b128
#pragma unroll
    for (int nt = 0; nt < 8; ++nt)
      c0[nt] = __builtin_amdgcn_mfma_f32_16x16x32_f16(ah, mh[cur][nt], c0[nt], 0, 0, 0);
  }

  // ---- store out[:, :128] = A0 + mix0 (64B-coalesced per quad group)
#pragma unroll
  for (int nt = 0; nt < 8; ++nt)
#pragma unroll
    for (int r = 0; r < 4; ++r) {
      const int n = cnode0 + r;
      if (n < n_nodes) out[(size_t)n * ACOLS + nt * 16 + row] = c0[nt][r];
    }
}

extern "C" void kernel_launch(void* const* d_in, const int* in_sizes, int n_in,
                              void* d_out, int out_size, void* d_ws, size_t ws_size,
                              hipStream_t stream) {
  const float* attrs = (const float*)d_in[0];
  const int*   eidx  = (const int*)d_in[1];
  const float* evec  = (const float*)d_in[2];
  const float* elen  = (const float*)d_in[3];
  const float* W1    = (const float*)d_in[4];
  const float* W2    = (const float*)d_in[5];
  const float* Wtp0  = (const float*)d_in[6];
  const float* Wtp1  = (const float*)d_in[7];
  const float* Wmix  = (const float*)d_in[8];
  float* out = (float*)d_out;

  const int n_nodes = in_sizes[0] / HIDDEN;
  const int n_edges = in_sizes[1] / 2;

  // ws: recs | TqB | cnt | off | cur | partial | bsums | lb | SG | P(96KB) | attrsB
  char* ws = (char*)d_ws;
  float4* recs = (float4*)ws;
  size_t o1 = (((size_t)n_edges * 32) + 255) & ~(size_t)255;
  ushort_t* TqB = (ushort_t*)(ws + o1);                       // (TBINS+1)*128 u32
  size_t o2 = (o1 + (size_t)(TBINS + 1) * HIDDEN * 4 + 255) & ~(size_t)255;
  int* cnt = (int*)(ws + o2);
  size_t o3 = (o2 + (size_t)n_nodes * 4 + 255) & ~(size_t)255;
  int* off = (int*)(ws + o3);
  size_t o4 = (o3 + (size_t)(n_nodes + 1) * 4 + 255) & ~(size_t)255;
  int* cur = (int*)(ws + o4);
  size_t o5 = (o4 + (size_t)n_nodes * 4 + 255) & ~(size_t)255;
  int* partial = (int*)(ws + o5);
  size_t o6 = (o5 + (size_t)n_nodes * 4 + 255) & ~(size_t)255;
  int* bsums = (int*)(ws + o6);
  size_t o6b = o6 + 1024 * 4;
  int* lb = (int*)(ws + o6b);                                 // NWAVES+1 ints
  size_t o7 = (o6b + (size_t)(NWAVES + 1) * 4 + 255) & ~(size_t)255;
  unsigned* SG = (unsigned*)(ws + o7);
  size_t o8 = o7 + (size_t)n_nodes * 1024;
  ushort_t* P = (ushort_t*)(ws + o8);
  size_t o9 = (o8 + 49152 * 2 + 255) & ~(size_t)255;
  unsigned* attrsB = (unsigned*)(ws + o9);                    // n_nodes*64 u32

  (void)hipMemsetAsync(cnt, 0, (size_t)n_nodes * 4, stream);
  const int n2 = n_nodes * 64;
  const int hist_blocks = (n_edges + 127) / 128;
  const int pack_blocks = (n2 + 127) / 128;
  tab_hist<<<TBINS + 1 + hist_blocks + pack_blocks, 128, 0, stream>>>(
      W1, W2, TqB, eidx + n_edges, cnt, n_edges, attrs, attrsB, n2, hist_blocks);
  const int nscan = (n_nodes + 1023) / 1024;
  scan_blocks<<<nscan, 1024, 0, stream>>>(cnt, partial, bsums, n_nodes);
  scan_sums<<<1, 1024, 0, stream>>>(bsums, nscan, off, n_nodes);
  scan_final<<<(n_nodes + 255) / 256, 256, 0, stream>>>(partial, bsums, off, cur,
                                                        n_nodes);
  const int edge_blocks = (n_edges + 255) / 256;
  const int wb_blocks = (NWAVES + 1 + 255) / 256;
  scatter_kernel<<<edge_blocks + wb_blocks, 256, 0, stream>>>(
      eidx, evec, elen, cur, recs, n_edges, off, lb, n_nodes, edge_blocks);
  pack_weights<<<192, 256, 0, stream>>>(Wtp0, Wtp1, Wmix, P);
  node_sg<<<2048, 512, 0, stream>>>(attrsB, (const unsigned*)TqB, recs, off, lb,
                                    SG, n_nodes);
  const int ntiles = (n_nodes + 15) / 16;
  node_mfma<<<ntiles, 64, 0, stream>>>((const ushort_t*)SG, P, out, n_nodes);
}

// Round 11
// 214.215 us; speedup vs baseline: 1.0502x; 1.0384x over previous
//
#include <hip/hip_runtime.h>
#include <math.h>

#define HIDDEN 128
#define MUL1   64
#define ACOLS  320   // HIDDEN + 3*MUL1
#define TBINS  4096
#define NWAVES 16384  // node_sg: 2048 blocks x 8 waves

typedef unsigned short ushort_t;
typedef __attribute__((ext_vector_type(8))) _Float16 f16x8;
typedef __attribute__((ext_vector_type(4))) float f32x4;

__device__ __forceinline__ unsigned short f2h(float x) {
  return __builtin_bit_cast(unsigned short, (_Float16)x);
}
__device__ __forceinline__ unsigned pack2h(float a, float b) {
  return (unsigned)f2h(a) | ((unsigned)f2h(b) << 16);
}
__device__ __forceinline__ float hlo(unsigned u) {
  return (float)__builtin_bit_cast(_Float16, (unsigned short)(u & 0xffffu));
}
__device__ __forceinline__ float hhi(unsigned u) {
  return (float)__builtin_bit_cast(_Float16, (unsigned short)(u >> 16));
}

// ---------------- K1: 4-range block multiplex (all independent):
//  [0..TBINS]                      R_n lerp table (packed fp16 pairs)
//  [+hist_blocks]                  receiver histogram
//  [+apack_blocks]                 attrs f32 -> fp16x2 (float4->uint2)
//  [+wpack_blocks]                 weights pre-scale -> fp16 MFMA B-frag order
__global__ __launch_bounds__(128) void tab_hist(
    const float* __restrict__ W1, const float* __restrict__ W2,
    ushort_t* __restrict__ TqB, const int* __restrict__ recv,
    int* __restrict__ cnt, int n_edges,
    const float* __restrict__ attrs, unsigned* __restrict__ attrsB, int n4,
    const float* __restrict__ Wtp0, const float* __restrict__ Wtp1,
    const float* __restrict__ Wmix, ushort_t* __restrict__ P,
    int hist_blocks, int apack_blocks) {
  const int tid = threadIdx.x;
  if (blockIdx.x > TBINS) {
    const int hb = blockIdx.x - (TBINS + 1);
    if (hb < hist_blocks) {                      // ---- histogram range
      const int e = hb * 128 + tid;
      if (e < n_edges) atomicAdd(&cnt[recv[e]], 1);
    } else if (hb < hist_blocks + apack_blocks) { // ---- attrs pack range
      const int i = (hb - hist_blocks) * 128 + tid;
      if (i < n4) {
        const float4 v = ((const float4*)attrs)[i];
        uint2 o; o.x = pack2h(v.x, v.y); o.y = pack2h(v.z, v.w);
        ((uint2*)attrsB)[i] = o;
      }
    } else {                                     // ---- weight pack range
      const int idx = (hb - hist_blocks - apack_blocks) * 128 + tid;  // 0..49151
      if (idx < 49152) {
        const int j = idx & 7, lane = (idx >> 3) & 63;
        const int krow = (lane >> 4) * 8 + j, col = lane & 15;
        float v;
        if (idx < 16384) {
          const int tq = idx >> 9, nt = tq >> 2, q = tq & 3;
          v = Wtp0[(krow + q * 32) * HIDDEN + nt * 16 + col] * 0.0883883476f;
        } else if (idx < 24576) {
          const int i2 = idx - 16384;
          const int tq = i2 >> 9, nt = tq >> 2, q = tq & 3;
          v = Wtp1[(krow + q * 32) * MUL1 + nt * 16 + col] * 0.0883883476f;
        } else {
          const int i3 = idx - 24576;
          const int tq = i3 >> 9, nt = tq / 6, q = tq % 6;
          v = Wmix[(krow + q * 32) * HIDDEN + nt * 16 + col] * 18.4752086f; // *2^8
        }
        P[idx] = f2h(v);
      }
    }
    return;
  }
  __shared__ float hsh[64];
  const int i = blockIdx.x;        // 0..TBINS
  const float x = (float)i * (5.0f / TBINS);
  if (tid < 64) {
    const bool valid = (x > 0.0f) && (x < 5.0f);
    const float invx = valid ? (1.0f / x) : 0.0f;
    float z = 0.0f;
#pragma unroll
    for (int r = 0; r < 8; ++r) {
      float arg = (float)(r + 1) * 0.6283185307f * x;     // k*pi*x/5
      float rad = 0.6324555320f * sinf(arg) * invx;       // sqrt(2/5)*sin/x
      z += rad * (W1[r * 64 + tid] * 0.3535533906f);      // W1/sqrt(8)
    }
    float sg = 1.0f / (1.0f + expf(-z));
    hsh[tid] = 1.679177f * z * sg;
  }
  __syncthreads();
  float acc = 0.0f;
  for (int j = 0; j < 64; ++j)
    acc += hsh[j] * W2[j * HIDDEN + tid];
  acc *= 0.125f;                                          // W2/8
  const ushort_t a16 = f2h(acc);
  TqB[((size_t)i * HIDDEN + tid) * 2] = a16;              // lo slot of row i
  if (i >= 1)
    TqB[((size_t)(i - 1) * HIDDEN + tid) * 2 + 1] = a16;  // hi slot of row i-1
}

// ---------------- K2a: per-block exclusive scan (1024 elems/block) ----------------
__global__ __launch_bounds__(1024) void scan_blocks(const int* __restrict__ cnt,
                                                    int* __restrict__ partial,
                                                    int* __restrict__ bsums, int n) {
  __shared__ int buf[1024];
  const int t = threadIdx.x;
  const int i = blockIdx.x * 1024 + t;
  const int v = (i < n) ? cnt[i] : 0;
  buf[t] = v;
  __syncthreads();
  for (int d = 1; d < 1024; d <<= 1) {
    const int x = buf[t];
    const int y = (t >= d) ? buf[t - d] : 0;
    __syncthreads();
    buf[t] = x + y;
    __syncthreads();
  }
  if (i < n) partial[i] = buf[t] - v;          // block-local exclusive
  if (t == 1023) bsums[blockIdx.x] = buf[1023];
}

// ---------------- K2b: single-block scan of block sums; writes off[n]=total ------
__global__ __launch_bounds__(1024) void scan_sums(int* __restrict__ bsums, int nb,
                                                  int* __restrict__ off, int n) {
  __shared__ int buf[1024];
  const int t = threadIdx.x;
  const int v = (t < nb) ? bsums[t] : 0;
  buf[t] = v;
  __syncthreads();
  for (int d = 1; d < 1024; d <<= 1) {
    const int x = buf[t];
    const int y = (t >= d) ? buf[t - d] : 0;
    __syncthreads();
    buf[t] = x + y;
    __syncthreads();
  }
  if (t < nb) bsums[t] = buf[t] - v;           // exclusive block offsets
  if (t == nb - 1) off[n] = buf[t];            // grand total
}

// ---------------- K2c: off/cur = partial + block offset ----------------
__global__ __launch_bounds__(256) void scan_final(const int* __restrict__ partial,
                                                  const int* __restrict__ bsums,
                                                  int* __restrict__ off,
                                                  int* __restrict__ cur, int n) {
  const int i = blockIdx.x * 256 + threadIdx.x;
  if (i < n) {
    const int o = partial[i] + bsums[i >> 10];
    off[i] = o;
    cur[i] = o;
  }
}

// ---------------- K3: build sorted 16B edge records + edge-balanced wave
// partition (2-range multiplex). rec16 layout:
//   x: s | (i0<<16)          (n_nodes<=65536, i0<4096)
//   y: fp16 {w0, w1}         (pre-zeroed when invalid)
//   z: fp16 {rb0, rb1}       (sqrt3 * unit[1,2,0])
//   w: fp16 {rb2, 0}
// 16B record halves scatter's random-write traffic and node_sg's s_load bytes;
// w/rb at fp16 matches the precision already committed by the fp16 table and
// fp16 G storage.
__global__ __launch_bounds__(256) void scatter_kernel(
    const int* __restrict__ eidx, const float* __restrict__ evec,
    const float* __restrict__ elen, int* __restrict__ cur,
    uint4* __restrict__ recs, int n_edges,
    const int* __restrict__ off, int* __restrict__ lb, int n_nodes,
    int edge_blocks) {
  if (blockIdx.x >= edge_blocks) {               // wave-partition range
    const int w = (blockIdx.x - edge_blocks) * 256 + threadIdx.x;
    if (w > NWAVES) return;
    if (w == NWAVES) { lb[w] = n_nodes; return; }
    const long long target = ((long long)w * (long long)n_edges) / NWAVES;
    int lo = 0, hi = n_nodes;
    while (lo < hi) {
      const int mid = (lo + hi) >> 1;
      if ((long long)off[mid] < target) lo = mid + 1; else hi = mid;
    }
    lb[w] = lo;
    return;
  }
  const int e = blockIdx.x * 256 + threadIdx.x;
  if (e >= n_edges) return;
  const int s = eidx[e], r = eidx[n_edges + e];
  const float x = elen[e];
  const float v0 = evec[3 * e], v1 = evec[3 * e + 1], v2 = evec[3 * e + 2];
  const float rn = rsqrtf(v0 * v0 + v1 * v1 + v2 * v2);
  const float u = x * ((float)TBINS / 5.0f);
  int i0 = (int)floorf(u);
  i0 = i0 < 0 ? 0 : (i0 > TBINS - 1 ? TBINS - 1 : i0);
  const float fr = u - (float)i0;
  const bool valid = (x > 0.0f) && (x < 5.0f);
  const float w0 = valid ? 1.0f - fr : 0.0f;
  const float w1 = valid ? fr : 0.0f;
  const int pos = atomicAdd(&cur[r], 1);
  uint4 rec;
  rec.x = (unsigned)(s & 0xFFFF) | ((unsigned)i0 << 16);
  rec.y = pack2h(w0, w1);
  rec.z = pack2h(1.7320508076f * v1 * rn, 1.7320508076f * v2 * rn);
  rec.w = pack2h(1.7320508076f * v0 * rn, 0.0f);
  recs[pos] = rec;
}

// ---------------- K5: pure gather: per node accumulate S (128) and G (128x3),
// write 1KB fp16 record. Scalarized uniform control + 8-edge epochs
// (16 gathers in flight); 16B recs -> 2 s_load_dwordx16 per epoch.
__global__ __launch_bounds__(512) void node_sg(
    const unsigned* __restrict__ attrsB, const unsigned* __restrict__ TqB,
    const uint4* __restrict__ recs, const int* __restrict__ off,
    const int* __restrict__ lb, unsigned* __restrict__ SG, int n_nodes) {
  const int lane = threadIdx.x & 63;
  const int wid = __builtin_amdgcn_readfirstlane((blockIdx.x << 3) +
                                                 (threadIdx.x >> 6));
  const int nbeg = lb[wid], nend = lb[wid + 1];
  const unsigned* tqb = TqB + 2 * lane;     // per-lane bases, loop-invariant
  const unsigned* atb = attrsB + lane;
  for (int n = nbeg; n < nend; ++n) {
    const int beg = off[n], end = off[n + 1];
    const int cnt = end - beg;
    float Sa = 0.f, Sb = 0.f;
    float Ga0 = 0.f, Ga1 = 0.f, Ga2 = 0.f, Gb0 = 0.f, Gb1 = 0.f, Gb2 = 0.f;
    int i = beg;
    // ---- main: 8-edge epochs, unpredicated (uniform scalar control)
    const int m8 = beg + (cnt & ~7);
    for (; i < m8; i += 8) {
      uint4 rc[8];
#pragma unroll
      for (int b = 0; b < 8; ++b) rc[b] = recs[i + b];     // uniform -> s_load
      uint2 tqv[8];
      unsigned avv[8];
#pragma unroll
      for (int b = 0; b < 8; ++b) {                        // 16 gathers in flight
        const unsigned sv = rc[b].x & 0xFFFFu;
        const unsigned i0 = rc[b].x >> 16;
        tqv[b] = *(const uint2*)(tqb + (i0 << 7));
        avv[b] = atb[sv << 6];
      }
#pragma unroll
      for (int b = 0; b < 8; ++b) {
        const float w0 = hlo(rc[b].y), w1 = hhi(rc[b].y);
        const float Ra = w0 * hlo(tqv[b].x) + w1 * hhi(tqv[b].x);
        const float Rb = w0 * hlo(tqv[b].y) + w1 * hhi(tqv[b].y);
        const float la = hlo(avv[b]) * Ra, lb2 = hhi(avv[b]) * Rb;
        const float r0 = hlo(rc[b].z), r1 = hhi(rc[b].z), r2 = hlo(rc[b].w);
        Sa += la; Sb += lb2;
        Ga0 += la * r0; Ga1 += la * r1; Ga2 += la * r2;
        Gb0 += lb2 * r0; Gb1 += lb2 * r1; Gb2 += lb2 * r2;
      }
    }
    // ---- 4-edge epoch if >=4 remain
    const int m4 = beg + (cnt & ~3);
    for (; i < m4; i += 4) {
      uint4 rc[4];
#pragma unroll
      for (int b = 0; b < 4; ++b) rc[b] = recs[i + b];
      uint2 tqv[4];
      unsigned avv[4];
#pragma unroll
      for (int b = 0; b < 4; ++b) {
        const unsigned sv = rc[b].x & 0xFFFFu;
        const unsigned i0 = rc[b].x >> 16;
        tqv[b] = *(const uint2*)(tqb + (i0 << 7));
        avv[b] = atb[sv << 6];
      }
#pragma unroll
      for (int b = 0; b < 4; ++b) {
        const float w0 = hlo(rc[b].y), w1 = hhi(rc[b].y);
        const float Ra = w0 * hlo(tqv[b].x) + w1 * hhi(tqv[b].x);
        const float Rb = w0 * hlo(tqv[b].y) + w1 * hhi(tqv[b].y);
        const float la = hlo(avv[b]) * Ra, lb2 = hhi(avv[b]) * Rb;
        const float r0 = hlo(rc[b].z), r1 = hhi(rc[b].z), r2 = hlo(rc[b].w);
        Sa += la; Sb += lb2;
        Ga0 += la * r0; Ga1 += la * r1; Ga2 += la * r2;
        Gb0 += lb2 * r0; Gb1 += lb2 * r1; Gb2 += lb2 * r2;
      }
    }
    // ---- tail: 0-3 single edges
    for (; i < end; ++i) {
      const uint4 rc = recs[i];
      const unsigned sv = rc.x & 0xFFFFu;
      const unsigned i0 = rc.x >> 16;
      const uint2 tq = *(const uint2*)(tqb + (i0 << 7));
      const unsigned av = atb[sv << 6];
      const float w0 = hlo(rc.y), w1 = hhi(rc.y);
      const float Ra = w0 * hlo(tq.x) + w1 * hhi(tq.x);
      const float Rb = w0 * hlo(tq.y) + w1 * hhi(tq.y);
      const float la = hlo(av) * Ra, lb2 = hhi(av) * Rb;
      const float r0 = hlo(rc.z), r1 = hhi(rc.z), r2 = hlo(rc.w);
      Sa += la; Sb += lb2;
      Ga0 += la * r0; Ga1 += la * r1; Ga2 += la * r2;
      Gb0 += lb2 * r0; Gb1 += lb2 * r1; Gb2 += lb2 * r2;
    }
    unsigned* srow = SG + (size_t)n * 256;        // 256 u32 = 512 fp16 per node
    srow[lane]       = pack2h(Sa, Sb);            // S[2l], S[2l+1]
    srow[64 + lane]  = pack2h(Ga0, Gb0);          // G_d0
    srow[128 + lane] = pack2h(Ga1, Gb1);          // G_d1
    srow[192 + lane] = pack2h(Ga2, Gb2);          // G_d2
  }
}

// ---------------- K6: wave-per-16-nodes MFMA (fp16 single precision):
// A0=S@W0', A1=G@W1', B0, c0+=B0@Wm'. 1-wave blocks; depth-3 register
// prefetch on the L2-resident P stream; fp16 B0s stage (6.4 KB LDS).
struct F3 { float x, y, z; };

__global__ __launch_bounds__(64, 2) void node_mfma(
    const ushort_t* __restrict__ SG, const ushort_t* __restrict__ P,
    float* __restrict__ out, int n_nodes) {
  __shared__ ushort_t B0s[16][200];   // fp16 B0 stage; stride 200 (16B-aligned rows)
  const int lane = threadIdx.x & 63;
  const int tile = blockIdx.x;
  const int row = lane & 15, quad = lane >> 4;
  const int nA = min(tile * 16 + row, n_nodes - 1);   // clamped A-row node
  const ushort_t* sgA = SG + (size_t)nA * 512;
  const int cnode0 = tile * 16 + quad * 4;            // C-frag rows

  const ushort_t* W0f = P;            // 16384
  const ushort_t* W1f = P + 16384;    // 8192
  const ushort_t* Wmf = P + 24576;    // 24576

  // ---- A-side fragments (issued up front; S row + 3 G rows)
  f16x8 aS[4], aG[3][4];
#pragma unroll
  for (int q = 0; q < 4; ++q)
    aS[q] = *(const f16x8*)(sgA + quad * 8 + q * 32);
#pragma unroll
  for (int d = 0; d < 3; ++d)
#pragma unroll
    for (int q = 0; q < 4; ++q)
      aG[d][q] = *(const f16x8*)(sgA + 128 + d * 128 + quad * 8 + q * 32);

  f32x4 c0[8];
#pragma unroll
  for (int nt = 0; nt < 8; ++nt) c0[nt] = (f32x4){0.f, 0.f, 0.f, 0.f};
  f32x4 c1[3][4];
#pragma unroll
  for (int d = 0; d < 3; ++d)
#pragma unroll
    for (int nt = 0; nt < 4; ++nt) c1[d][nt] = (f32x4){0.f, 0.f, 0.f, 0.f};

  // ---- Phase 1: A0 = S @ W0' (M=16, N=128, K=128). depth-3 prefetch.
  {
    f16x8 pb[3][4];
#pragma unroll
    for (int nt = 0; nt < 2; ++nt)
#pragma unroll
      for (int q = 0; q < 4; ++q)
        pb[nt][q] = *(const f16x8*)(W0f + ((nt * 4 + q) * 64 + lane) * 8);
#pragma unroll
    for (int nt = 0; nt < 8; ++nt) {
      const int cur = nt % 3;
      if (nt < 6) {
        const int dst = (nt + 2) % 3;
#pragma unroll
        for (int q = 0; q < 4; ++q)
          pb[dst][q] = *(const f16x8*)(W0f + (((nt + 2) * 4 + q) * 64 + lane) * 8);
      }
#pragma unroll
      for (int q = 0; q < 4; ++q)
        c0[nt] = __builtin_amdgcn_mfma_f32_16x16x32_f16(aS[q], pb[cur][q], c0[nt], 0, 0, 0);
    }
  }

  // ---- Phase 2: A1_d = G_d @ W1' (3 x [M=16, N=64, K=128]). depth-3 prefetch.
  {
    f16x8 pb[3][4];
#pragma unroll
    for (int nt = 0; nt < 2; ++nt)
#pragma unroll
      for (int q = 0; q < 4; ++q)
        pb[nt][q] = *(const f16x8*)(W1f + ((nt * 4 + q) * 64 + lane) * 8);
#pragma unroll
    for (int nt = 0; nt < 4; ++nt) {
      const int cur = nt % 3;
      if (nt < 2) {
        const int dst = (nt + 2) % 3;
#pragma unroll
        for (int q = 0; q < 4; ++q)
          pb[dst][q] = *(const f16x8*)(W1f + (((nt + 2) * 4 + q) * 64 + lane) * 8);
      }
#pragma unroll
      for (int q = 0; q < 4; ++q)
#pragma unroll
        for (int d = 0; d < 3; ++d)
          c1[d][nt] = __builtin_amdgcn_mfma_f32_16x16x32_f16(aG[d][q], pb[cur][q], c1[d][nt], 0, 0, 0);
    }
  }

  // ---- store A1 (out cols 128+3m+d) as one 12B store per (nt,r)
#pragma unroll
  for (int nt = 0; nt < 4; ++nt) {
    const int m = nt * 16 + row;
#pragma unroll
    for (int r = 0; r < 4; ++r) {
      const int n = cnode0 + r;
      if (n < n_nodes) {
        F3 v3 = {c1[0][nt][r], c1[1][nt][r], c1[2][nt][r]};
        *(F3*)&out[(size_t)n * ACOLS + HIDDEN + 3 * m] = v3;
      }
    }
  }

  // ---- build B0*2^-8 (fp16) in LDS (C-layout -> A-layout transpose).
  // 2^-4 before squaring = exact 2^-8 on B0; compensated by 2^8 in Wmf.
#pragma unroll
  for (int nt = 0; nt < 8; ++nt)
#pragma unroll
    for (int r = 0; r < 4; ++r) {
      const float a = c0[nt][r] * 0.0625f;
      B0s[quad * 4 + r][nt * 16 + row] = f2h(a * a);
    }
#pragma unroll
  for (int nt = 0; nt < 4; ++nt)
#pragma unroll
    for (int r = 0; r < 4; ++r) {
      const float x = c1[0][nt][r] * 0.0625f, y = c1[1][nt][r] * 0.0625f,
                  z = c1[2][nt][r] * 0.0625f;
      B0s[quad * 4 + r][HIDDEN + nt * 16 + row] =
          f2h((x * x + y * y + z * z) * 0.5773502692f);   // /sqrt(3), *2^-8
    }

  // ---- Phase 3: c0 += B0 @ Wm' (K=192). Issue q=0/1 B-frag loads BEFORE the
  // LDS wait so they fly during the LDS drain.
  f16x8 mh[3][8];
#pragma unroll
  for (int qq = 0; qq < 2; ++qq)
#pragma unroll
    for (int nt = 0; nt < 8; ++nt)
      mh[qq][nt] = *(const f16x8*)(Wmf + ((nt * 6 + qq) * 64 + lane) * 8);

  // wave-private LDS: only this wave's ds_writes must complete (no barrier).
  asm volatile("s_waitcnt lgkmcnt(0)" ::: "memory");
  __builtin_amdgcn_sched_barrier(0);

#pragma unroll
  for (int q = 0; q < 6; ++q) {
    const int cur = q % 3;
    if (q < 4) {
      const int dst = (q + 2) % 3;
#pragma unroll
      for (int nt = 0; nt < 8; ++nt)
        mh[dst][nt] = *(const f16x8*)(Wmf + ((nt * 6 + (q + 2)) * 64 + lane) * 8);
    }
    const f16x8 ah = *(const f16x8*)&B0s[row][quad * 8 + q * 32];  // ds_read_b128
#pragma unroll
    for (int nt = 0; nt < 8; ++nt)
      c0[nt] = __builtin_amdgcn_mfma_f32_16x16x32_f16(ah, mh[cur][nt], c0[nt], 0, 0, 0);
  }

  // ---- store out[:, :128] = A0 + mix0 (64B-coalesced per quad group)
#pragma unroll
  for (int nt = 0; nt < 8; ++nt)
#pragma unroll
    for (int r = 0; r < 4; ++r) {
      const int n = cnode0 + r;
      if (n < n_nodes) out[(size_t)n * ACOLS + nt * 16 + row] = c0[nt][r];
    }
}

extern "C" void kernel_launch(void* const* d_in, const int* in_sizes, int n_in,
                              void* d_out, int out_size, void* d_ws, size_t ws_size,
                              hipStream_t stream) {
  const float* attrs = (const float*)d_in[0];
  const int*   eidx  = (const int*)d_in[1];
  const float* evec  = (const float*)d_in[2];
  const float* elen  = (const float*)d_in[3];
  const float* W1    = (const float*)d_in[4];
  const float* W2    = (const float*)d_in[5];
  const float* Wtp0  = (const float*)d_in[6];
  const float* Wtp1  = (const float*)d_in[7];
  const float* Wmix  = (const float*)d_in[8];
  float* out = (float*)d_out;

  const int n_nodes = in_sizes[0] / HIDDEN;
  const int n_edges = in_sizes[1] / 2;

  // ws: recs16 | TqB | cnt | off | cur | partial | bsums | lb | SG | P(96KB) | attrsB
  char* ws = (char*)d_ws;
  uint4* recs = (uint4*)ws;                                   // 16B/edge
  size_t o1 = (((size_t)n_edges * 16) + 255) & ~(size_t)255;
  ushort_t* TqB = (ushort_t*)(ws + o1);                       // (TBINS+1)*128 u32
  size_t o2 = (o1 + (size_t)(TBINS + 1) * HIDDEN * 4 + 255) & ~(size_t)255;
  int* cnt = (int*)(ws + o2);
  size_t o3 = (o2 + (size_t)n_nodes * 4 + 255) & ~(size_t)255;
  int* off = (int*)(ws + o3);
  size_t o4 = (o3 + (size_t)(n_nodes + 1) * 4 + 255) & ~(size_t)255;
  int* cur = (int*)(ws + o4);
  size_t o5 = (o4 + (size_t)n_nodes * 4 + 255) & ~(size_t)255;
  int* partial = (int*)(ws + o5);
  size_t o6 = (o5 + (size_t)n_nodes * 4 + 255) & ~(size_t)255;
  int* bsums = (int*)(ws + o6);
  size_t o6b = o6 + 1024 * 4;
  int* lb = (int*)(ws + o6b);                                 // NWAVES+1 ints
  size_t o7 = (o6b + (size_t)(NWAVES + 1) * 4 + 255) & ~(size_t)255;
  unsigned* SG = (unsigned*)(ws + o7);
  size_t o8 = o7 + (size_t)n_nodes * 1024;
  ushort_t* P = (ushort_t*)(ws + o8);
  size_t o9 = (o8 + 49152 * 2 + 255) & ~(size_t)255;
  unsigned* attrsB = (unsigned*)(ws + o9);                    // n_nodes*64 u32

  (void)hipMemsetAsync(cnt, 0, (size_t)n_nodes * 4, stream);
  const int n4 = n_nodes * 32;                                // float4 packs
  const int hist_blocks = (n_edges + 127) / 128;
  const int apack_blocks = (n4 + 127) / 128;
  const int wpack_blocks = (49152 + 127) / 128;
  tab_hist<<<TBINS + 1 + hist_blocks + apack_blocks + wpack_blocks, 128, 0,
             stream>>>(W1, W2, TqB, eidx + n_edges, cnt, n_edges, attrs, attrsB,
                       n4, Wtp0, Wtp1, Wmix, P, hist_blocks, apack_blocks);
  const int nscan = (n_nodes + 1023) / 1024;
  scan_blocks<<<nscan, 1024, 0, stream>>>(cnt, partial, bsums, n_nodes);
  scan_sums<<<1, 1024, 0, stream>>>(bsums, nscan, off, n_nodes);
  scan_final<<<(n_nodes + 255) / 256, 256, 0, stream>>>(partial, bsums, off, cur,
                                                        n_nodes);
  const int edge_blocks = (n_edges + 255) / 256;
  const int wb_blocks = (NWAVES + 1 + 255) / 256;
  scatter_kernel<<<edge_blocks + wb_blocks, 256, 0, stream>>>(
      eidx, evec, elen, cur, recs, n_edges, off, lb, n_nodes, edge_blocks);
  node_sg<<<2048, 512, 0, stream>>>(attrsB, (const unsigned*)TqB, recs, off, lb,
                                    SG, n_nodes);
  const int ntiles = (n_nodes + 15) / 16;
  node_mfma<<<ntiles, 64, 0, stream>>>((const ushort_t*)SG, P, out, n_nodes);
}